// Round 1
// baseline (63.133 us; speedup 1.0000x reference)
//
#include <hip/hip_runtime.h>

// ROI max pooling, TF-style slicing/binning semantics:
//   half = floor(size/2); start = int(center-half); end = int(center+half)
//   len = end-start; step = max(len/7, 1)
//   bin k<6: rel [k*step,(k+1)*step); bin 6: [6*step, len)
//
// R1: wave-uniform loop control forced into SGPRs via readfirstlane so the
// per-iteration p/nx recurrence + row addressing runs on the scalar pipe,
// and loads use saddr-form (uniform base + 32-bit voffset). Per-iteration
// VALU: 1 v_min + 2 addr + 4 v_max_f32 (was ~14).
#define PH 7
#define PW 7
#define BB 2
#define NN 96
#define HH 64
#define WW 64
#define CC 128   // 32 float4s per pixel, 512 B per pixel

__global__ __launch_bounds__(256) void roi_pool_kernel(
    const float* __restrict__ fm,    // [B,H,W,C]
    const float* __restrict__ rois,  // [B,N,4] = [xc,yc,w,h]
    float* __restrict__ out)         // [B,N,PH,PW,C]
{
    const int wid  = threadIdx.x >> 6;            // wave 0..3 within block
    const int lane = threadIdx.x & 63;
    const int bin  = blockIdx.x * 4 + wid;        // global bin id, 0..9407

    const int pw  = bin % PW;
    int t         = bin / PW;
    const int ph  = t % PH;
    const int roi = t / PH;                       // b*N + n
    const int b   = roi / NN;

    const float4 r = ((const float4*)rois)[roi];
    const float half_w = floorf(r.z * 0.5f);
    const float half_h = floorf(r.w * 0.5f);
    const int sx = (int)(r.x - half_w);
    const int ex = (int)(r.x + half_w);
    const int sy = (int)(r.y - half_h);
    const int ey = (int)(r.y + half_h);
    const int stx = max((ex - sx) / PW, 1);
    const int sty = max((ey - sy) / PH, 1);

    int x0 = sx + pw * stx;
    int x1 = (pw == PW - 1) ? ex : (x0 + stx);
    int y0 = sy + ph * sty;
    int y1 = (ph == PH - 1) ? ey : (y0 + sty);
    x0 = max(x0, 0); x1 = min(x1, WW);
    y0 = max(y0, 0); y1 = min(y1, HH);

    // lane -> (x offset 0/1, channel quad 0..31); wave covers 2 pixels/slot
    const int xo    = lane >> 5;
    const int laneq = (lane & 31) << 4;           // channel-quad byte offset

    // Flatten window to P = ny*nx slots; slot p -> row p/nx, x-pair p%nx.
    const int nx_v = (x1 - x0 + 1) >> 1;          // pairs per row (<= 6)
    const int ny_v = y1 - y0;

    // All of these are wave-uniform by construction (bin geometry), but the
    // compiler can't prove it (derived from threadIdx). Pin them to SGPRs.
    const int P    = __builtin_amdgcn_readfirstlane(max(nx_v * ny_v, 1));
    const int nx   = __builtin_amdgcn_readfirstlane(nx_v);
    const int xmax = __builtin_amdgcn_readfirstlane(x1 - 1 - x0);
    // byte offset of window-origin pixel, incl. batch (b*2MB + ... < 4MB, 32-bit)
    const int ub   = __builtin_amdgcn_readfirstlane(
        ((b * HH + y0) * WW + x0) * (CC * 4));
    // exact reciprocal for /nx: valid for p*nx < 65536 (p <= ~60, nx <= 6)
    const unsigned rcp = (65536u + (unsigned)nx - 1u) / (unsigned)nx;

    float4 m = make_float4(-INFINITY, -INFINITY, -INFINITY, -INFINITY);
    const char* fmb = (const char*)fm;            // uniform SGPR base -> saddr loads

#pragma unroll 4
    for (int p = 0; p < P; ++p) {
        const int yy   = (int)(((unsigned)p * rcp) >> 16);   // p / nx   (SALU)
        const int rem  = p - yy * nx;                        // p % nx   (SALU)
        const int uoff = ub + yy * (WW * CC * 4) + (rem << 10); // row/pair (SALU)
        const int col  = min(xo, xmax - (rem << 1));         // clamp dup: max-safe
        const float4 v = *(const float4*)(
            fmb + (size_t)(unsigned)(uoff + (col << 9) + laneq));
        m.x = fmaxf(m.x, v.x);
        m.y = fmaxf(m.y, v.y);
        m.z = fmaxf(m.z, v.z);
        m.w = fmaxf(m.w, v.w);
    }

    // combine the two half-waves (even/odd pixel columns, same channels)
    m.x = fmaxf(m.x, __shfl_xor(m.x, 32));
    m.y = fmaxf(m.y, __shfl_xor(m.y, 32));
    m.z = fmaxf(m.z, __shfl_xor(m.z, 32));
    m.w = fmaxf(m.w, __shfl_xor(m.w, 32));

    if (lane < 32) {
        *(float4*)((char*)out + (size_t)(unsigned)((bin << 9) + laneq)) = m;
    }
}

extern "C" void kernel_launch(void* const* d_in, const int* in_sizes, int n_in,
                              void* d_out, int out_size, void* d_ws, size_t ws_size,
                              hipStream_t stream) {
    const float* fm   = (const float*)d_in[0];
    const float* rois = (const float*)d_in[1];
    float* out = (float*)d_out;
    const int nbins = BB * NN * PH * PW;          // 9408 bins, 4 per block
    roi_pool_kernel<<<nbins / 4, 256, 0, stream>>>(fm, rois, out);
}